// Round 1
// baseline (82.733 us; speedup 1.0000x reference)
//
#include <hip/hip_runtime.h>
#include <math.h>

#define EPSF 1e-6f
#define MUF 18.0f
// 2*SIGMA^2 = 128
#define INV_2SIG2 (1.0f / 128.0f)

__device__ __forceinline__ float fexp2(float x) {
#if __has_builtin(__builtin_amdgcn_exp2f)
    return __builtin_amdgcn_exp2f(x);   // v_exp_f32
#else
    return exp2f(x);
#endif
}

// ---------------- prep: per-point weight + global reductions ----------------
// pts[i] = {x, y, z, w_unnormalized}  for i in [0, 2n)  (source then target)
// S[6] (doubles, pre-zeroed): {S1=sum|x|^2, Svx, Svy, Svz, sum_ws, sum_wt}
__global__ __launch_bounds__(256) void prep_kernel(
        const float* __restrict__ src, const float* __restrict__ tgt,
        int n, float4* __restrict__ pts, double* __restrict__ S) {
    int i = blockIdx.x * blockDim.x + threadIdx.x;
    double acc[6] = {0, 0, 0, 0, 0, 0};
    if (i < 2 * n) {
        const float* p = (i < n) ? (src + 3 * i) : (tgt + 3 * (i - n));
        float x = p[0], y = p[1], z = p[2];
        float phi = 2.0f * x + y + 1.0f / (z + EPSF);
        float dphi = phi - MUF;
        float w = expf(-(dphi * dphi) * INV_2SIG2);
        pts[i] = make_float4(x, y, z, w);
        float sq = x * x + y * y + z * z;
        acc[0] = (double)sq;
        acc[1] = (double)x;
        acc[2] = (double)y;
        acc[3] = (double)z;
        if (i < n) acc[4] = (double)w; else acc[5] = (double)w;
    }
    // wave64 butterfly-free down-reduce; lane 0 atomically accumulates
    #pragma unroll
    for (int k = 0; k < 6; ++k) {
        double v = acc[k];
        for (int off = 32; off > 0; off >>= 1) v += __shfl_down(v, off);
        if ((threadIdx.x & 63) == 0) atomicAdd(&S[k], v);
    }
}

// ---------------- main: 4096x4096 pairwise kernel sum ----------------
// grid = (n/256, n/64); block = 256. Thread owns one source point,
// loops over 64 LDS-staged target points (uniform index -> LDS broadcast).
__global__ __launch_bounds__(256) void main_kernel(
        const float4* __restrict__ pts, int n,
        const double* __restrict__ S, double* __restrict__ partials) {
    // bandwidth from closed form: sum(L2) = 2*nt*S1 - 2*|Sv|^2
    double nt = 2.0 * (double)n;
    double sumL2 = 2.0 * nt * S[0] - 2.0 * (S[1] * S[1] + S[2] * S[2] + S[3] * S[3]);
    double bw = sumL2 / (nt * nt - nt);
    bw = bw * 0.25;  // / KERNEL_MUL^(KERNEL_NUM//2) = / 4
    float m = (float)(-1.4426950408889634 / bw);  // u = d*m; term_i = exp2(u * 2^-i)

    __shared__ float4 tg[64];
    int tid = threadIdx.x;
    int sIdx = blockIdx.x * 256 + tid;
    int tBase = n + blockIdx.y * 64;
    if (tid < 64) tg[tid] = pts[tBase + tid];
    __syncthreads();

    float4 sp = pts[sIdx];
    float a0 = 0.0f;
    #pragma unroll 4
    for (int j = 0; j < 64; ++j) {
        float4 t = tg[j];
        float dx = sp.x - t.x;
        float dy = sp.y - t.y;
        float dz = sp.z - t.z;
        float d = dx * dx + dy * dy + dz * dz;
        float u = d * m;
        float k = fexp2(u)
                + fexp2(u * 0.5f)
                + fexp2(u * 0.25f)
                + fexp2(u * 0.125f)
                + fexp2(u * 0.0625f);
        a0 += t.w * k;
    }
    float thread_sum = a0 * sp.w;

    // block reduce (double) -> one partial per block, no atomics
    double v = (double)thread_sum;
    for (int off = 32; off > 0; off >>= 1) v += __shfl_down(v, off);
    __shared__ double wsum[4];
    if ((tid & 63) == 0) wsum[tid >> 6] = v;
    __syncthreads();
    if (tid == 0) {
        partials[blockIdx.y * gridDim.x + blockIdx.x] =
            wsum[0] + wsum[1] + wsum[2] + wsum[3];
    }
}

// ---------------- finalize: sum partials, normalize, write loss ----------------
__global__ __launch_bounds__(256) void fin_kernel(
        const double* __restrict__ S, const double* __restrict__ partials,
        int np, float* __restrict__ out) {
    int tid = threadIdx.x;
    double a = 0.0;
    for (int i = tid; i < np; i += 256) a += partials[i];
    for (int off = 32; off > 0; off >>= 1) a += __shfl_down(a, off);
    __shared__ double wsum[4];
    if ((tid & 63) == 0) wsum[tid >> 6] = a;
    __syncthreads();
    if (tid == 0) {
        double tot = wsum[0] + wsum[1] + wsum[2] + wsum[3];
        double denom = (S[4] + (double)EPSF) * (S[5] + (double)EPSF);
        out[0] = (float)(-2.0 * tot / denom);
    }
}

extern "C" void kernel_launch(void* const* d_in, const int* in_sizes, int n_in,
                              void* d_out, int out_size, void* d_ws, size_t ws_size,
                              hipStream_t stream) {
    const float* src = (const float*)d_in[0];
    const float* tgt = (const float*)d_in[1];
    int n = in_sizes[0] / 3;          // 4096
    float* out = (float*)d_out;

    // ws layout: [0, 2n*16) float4 pts | 6 doubles S | partials
    char* ws = (char*)d_ws;
    float4* pts = (float4*)ws;
    size_t off_S = (size_t)(2 * n) * sizeof(float4);
    double* S = (double*)(ws + off_S);
    double* partials = (double*)(ws + off_S + 8 * sizeof(double));

    int gx = (n + 255) / 256;   // 16 source chunks
    int gy = (n + 63) / 64;     // 64 target chunks
    int np = gx * gy;           // 1024 partials

    hipMemsetAsync(S, 0, 6 * sizeof(double), stream);
    prep_kernel<<<(2 * n + 255) / 256, 256, 0, stream>>>(src, tgt, n, pts, S);
    main_kernel<<<dim3(gx, gy), 256, 0, stream>>>(pts, n, S, partials);
    fin_kernel<<<1, 256, 0, stream>>>(S, partials, np, out);
}